// Round 1
// baseline (722.292 us; speedup 1.0000x reference)
//
#include <hip/hip_runtime.h>

#define B_   4
#define S_   2048
#define D_   1024
#define DFF_ 4096

typedef __attribute__((ext_vector_type(8))) short short8;
typedef __attribute__((ext_vector_type(4))) float floatx4;

__device__ __forceinline__ unsigned short f2b(float f) {
    unsigned int u = __float_as_uint(f);
    unsigned int r = (u + 0x7fffu + ((u >> 16) & 1u)) >> 16;
    return (unsigned short)r;
}

// ---------------------------------------------------------------------------
// cast fp32 -> bf16, vectorized (float4 in, ushort4 out)
// ---------------------------------------------------------------------------
__global__ __launch_bounds__(256) void cast_bf16_kernel(
    const float4* __restrict__ src, ushort4* __restrict__ dst, int n4)
{
    int i = blockIdx.x * 256 + threadIdx.x;
    if (i < n4) {
        float4 f = src[i];
        ushort4 u;
        u.x = f2b(f.x); u.y = f2b(f.y); u.z = f2b(f.z); u.w = f2b(f.w);
        dst[i] = u;
    }
}

// ---------------------------------------------------------------------------
// transpose + cast: W [K,N] fp32 row-major -> Wt [N,K] bf16 row-major
// block (32,8), 32x32 tile, +1 pad
// ---------------------------------------------------------------------------
__global__ __launch_bounds__(256) void transpose_cast_kernel(
    const float* __restrict__ W, unsigned short* __restrict__ Wt, int K, int N)
{
    __shared__ float tile[32][33];
    const int tx = threadIdx.x;  // 0..31
    const int ty = threadIdx.y;  // 0..7
    const int bx = blockIdx.x * 32;  // n offset
    const int by = blockIdx.y * 32;  // k offset
#pragma unroll
    for (int j = 0; j < 32; j += 8)
        tile[ty + j][tx] = W[(long long)(by + ty + j) * N + bx + tx];
    __syncthreads();
#pragma unroll
    for (int j = 0; j < 32; j += 8)
        Wt[(long long)(bx + ty + j) * K + by + tx] = f2b(tile[tx][ty + j]);
}

// ---------------------------------------------------------------------------
// GEMM: C[M,N](+z*sC) = act( scale * A[M,K](+z*sA) @ Bt[N,K](+z*sB)^T + bias )
// bf16 inputs, fp32 accum. 128x128 tile, BK=32, 4 waves, each wave 64x64.
// global_load_lds width-16 staging (m97 structure).
// TRANS: store C transposed per batch: C[b][n][s], b = row/sLen, s = row%sLen
// ---------------------------------------------------------------------------
template <int OUT_BF16, int ACT_LEAKY, int TRANS, int HAS_BIAS>
__global__ __launch_bounds__(256) void gemm_bt(
    const unsigned short* __restrict__ A,
    const unsigned short* __restrict__ Bt,
    void* __restrict__ Cptr,
    const float* __restrict__ bias,
    int M, int N, int K, float scale,
    long long sA, long long sB, long long sC, int sLen)
{
    __shared__ unsigned short As[128 * 32];
    __shared__ unsigned short Bs[128 * 32];

    const int tid  = threadIdx.x;
    const int lane = tid & 63;
    const int wave = tid >> 6;
    const int z    = blockIdx.z;

    A  += (long long)z * sA;
    Bt += (long long)z * sB;

    const int m0 = blockIdx.y * 128;
    const int n0 = blockIdx.x * 128;

    // staging: thread t loads 8 bf16 at row t/4, col (t%4)*8; 2 passes (+64 rows)
    const int ra = tid >> 2;
    const int ca = (tid & 3) * 8;
    const unsigned short* gA = A  + (long long)(m0 + ra) * K + ca;
    const unsigned short* gB = Bt + (long long)(n0 + ra) * K + ca;
    const long long pass2 = 64LL * K;

    unsigned short* lA = &As[wave * 512];
    unsigned short* lB = &Bs[wave * 512];

    floatx4 acc[4][4];
#pragma unroll
    for (int i = 0; i < 4; i++)
#pragma unroll
        for (int j = 0; j < 4; j++) acc[i][j] = floatx4{0.f, 0.f, 0.f, 0.f};

    const int wr = (wave >> 1) * 64;  // wave row offset inside 128-tile
    const int wc = (wave & 1) * 64;   // wave col offset
    const int fr = lane & 15;         // fragment row (m or n)
    const int fk = (lane >> 4) * 8;   // fragment k offset

    for (int k0 = 0; k0 < K; k0 += 32) {
        __syncthreads();
        __builtin_amdgcn_global_load_lds(
            (const __attribute__((address_space(1))) void*)(gA + k0),
            (__attribute__((address_space(3))) void*)lA, 16, 0, 0);
        __builtin_amdgcn_global_load_lds(
            (const __attribute__((address_space(1))) void*)(gA + k0 + pass2),
            (__attribute__((address_space(3))) void*)(lA + 2048), 16, 0, 0);
        __builtin_amdgcn_global_load_lds(
            (const __attribute__((address_space(1))) void*)(gB + k0),
            (__attribute__((address_space(3))) void*)lB, 16, 0, 0);
        __builtin_amdgcn_global_load_lds(
            (const __attribute__((address_space(1))) void*)(gB + k0 + pass2),
            (__attribute__((address_space(3))) void*)(lB + 2048), 16, 0, 0);
        __syncthreads();

        short8 af[4], bfr[4];
#pragma unroll
        for (int mi = 0; mi < 4; mi++)
            af[mi] = *(const short8*)&As[(wr + mi * 16 + fr) * 32 + fk];
#pragma unroll
        for (int ni = 0; ni < 4; ni++)
            bfr[ni] = *(const short8*)&Bs[(wc + ni * 16 + fr) * 32 + fk];

#pragma unroll
        for (int mi = 0; mi < 4; mi++)
#pragma unroll
            for (int ni = 0; ni < 4; ni++)
                acc[mi][ni] = __builtin_amdgcn_mfma_f32_16x16x32_bf16(
                    af[mi], bfr[ni], acc[mi][ni], 0, 0, 0);
    }

    // epilogue: C/D layout col=lane&15, row=(lane>>4)*4+reg
    const int cr = (lane >> 4) * 4;
    const int cc = lane & 15;
    float* Cf = (float*)Cptr;
    unsigned short* Cb = (unsigned short*)Cptr;

#pragma unroll
    for (int mi = 0; mi < 4; mi++) {
#pragma unroll
        for (int ni = 0; ni < 4; ni++) {
            const int col = n0 + wc + ni * 16 + cc;
            const float bv = HAS_BIAS ? bias[col] : 0.0f;
#pragma unroll
            for (int r = 0; r < 4; r++) {
                const int row = m0 + wr + mi * 16 + cr + r;
                float v = acc[mi][ni][r] * scale + bv;
                if (ACT_LEAKY) v = (v > 0.0f) ? v : 0.01f * v;
                long long idx;
                if (TRANS) {
                    const int bb = row / sLen;
                    const int ss = row - bb * sLen;
                    idx = ((long long)bb * N + col) * sLen + ss;
                } else {
                    idx = (long long)z * sC + (long long)row * N + col;
                }
                if (OUT_BF16) Cb[idx] = f2b(v); else Cf[idx] = v;
            }
        }
    }
}

// ---------------------------------------------------------------------------
// softmax over rows of scores [B*S, S] + intensity, write bf16 attn
// one block (256 thr) per row; S=2048 -> 8 elems/thread
// ---------------------------------------------------------------------------
__global__ __launch_bounds__(256) void softmax_bias_kernel(
    const float* __restrict__ scores, const float* __restrict__ intensity,
    unsigned short* __restrict__ attn)
{
    __shared__ float red[8];
    const long long row = blockIdx.x;
    const int tid = threadIdx.x;
    const float4* s4 = (const float4*)(scores + row * S_);
    const float4* i4 = (const float4*)(intensity + row * S_);
    ushort4* dst = (ushort4*)(attn + row * S_);

    float vv[8];
    {
        float4 a = s4[tid], b = s4[tid + 256];
        vv[0] = a.x; vv[1] = a.y; vv[2] = a.z; vv[3] = a.w;
        vv[4] = b.x; vv[5] = b.y; vv[6] = b.z; vv[7] = b.w;
    }

    float mx = vv[0];
#pragma unroll
    for (int i = 1; i < 8; i++) mx = fmaxf(mx, vv[i]);
#pragma unroll
    for (int o = 32; o > 0; o >>= 1) mx = fmaxf(mx, __shfl_xor(mx, o));
    if ((tid & 63) == 0) red[tid >> 6] = mx;
    __syncthreads();
    mx = fmaxf(fmaxf(red[0], red[1]), fmaxf(red[2], red[3]));

    float e[8];
    float sum = 0.f;
#pragma unroll
    for (int i = 0; i < 8; i++) { e[i] = __expf(vv[i] - mx); sum += e[i]; }
#pragma unroll
    for (int o = 32; o > 0; o >>= 1) sum += __shfl_xor(sum, o);
    if ((tid & 63) == 0) red[4 + (tid >> 6)] = sum;
    __syncthreads();
    sum = red[4] + red[5] + red[6] + red[7];
    const float rs = 1.0f / sum;

#pragma unroll
    for (int i = 0; i < 2; i++) {
        float4 iv = i4[tid + 256 * i];
        ushort4 o;
        o.x = f2b(e[4 * i + 0] * rs + iv.x);
        o.y = f2b(e[4 * i + 1] * rs + iv.y);
        o.z = f2b(e[4 * i + 2] * rs + iv.z);
        o.w = f2b(e[4 * i + 3] * rs + iv.w);
        dst[tid + 256 * i] = o;
    }
}

// ---------------------------------------------------------------------------
// LayerNorm(x + resid) * g + b ; writes fp32 out and optional bf16 out
// one block per row, D=1024 -> 4 elems/thread
// ---------------------------------------------------------------------------
__global__ __launch_bounds__(256) void ln_kernel(
    const float* __restrict__ x, const float* __restrict__ resid,
    const float* __restrict__ g, const float* __restrict__ b,
    float* __restrict__ out_f, unsigned short* __restrict__ out_b)
{
    __shared__ float red[8];
    const long long row = blockIdx.x;
    const int tid = threadIdx.x;
    const float4 xv = ((const float4*)(x + row * D_))[tid];
    const float4 rv = ((const float4*)(resid + row * D_))[tid];
    float v0 = xv.x + rv.x, v1 = xv.y + rv.y, v2 = xv.z + rv.z, v3 = xv.w + rv.w;

    float s = v0 + v1 + v2 + v3;
#pragma unroll
    for (int o = 32; o > 0; o >>= 1) s += __shfl_xor(s, o);
    if ((tid & 63) == 0) red[tid >> 6] = s;
    __syncthreads();
    const float mean = (red[0] + red[1] + red[2] + red[3]) * (1.0f / D_);

    const float d0 = v0 - mean, d1 = v1 - mean, d2 = v2 - mean, d3 = v3 - mean;
    float q = d0 * d0 + d1 * d1 + d2 * d2 + d3 * d3;
#pragma unroll
    for (int o = 32; o > 0; o >>= 1) q += __shfl_xor(q, o);
    if ((tid & 63) == 0) red[4 + (tid >> 6)] = q;
    __syncthreads();
    const float var = (red[4] + red[5] + red[6] + red[7]) * (1.0f / D_);
    const float inv = rsqrtf(var + 1e-6f);

    const float4 gv = ((const float4*)g)[tid];
    const float4 bv = ((const float4*)b)[tid];
    const float o0 = d0 * inv * gv.x + bv.x;
    const float o1 = d1 * inv * gv.y + bv.y;
    const float o2 = d2 * inv * gv.z + bv.z;
    const float o3 = d3 * inv * gv.w + bv.w;

    ((float4*)(out_f + row * D_))[tid] = float4{o0, o1, o2, o3};
    if (out_b) {
        ushort4 u; u.x = f2b(o0); u.y = f2b(o1); u.z = f2b(o2); u.w = f2b(o3);
        ((ushort4*)(out_b + row * D_))[tid] = u;
    }
}

// ---------------------------------------------------------------------------
extern "C" void kernel_launch(void* const* d_in, const int* in_sizes, int n_in,
                              void* d_out, int out_size, void* d_ws, size_t ws_size,
                              hipStream_t stream)
{
    const float* X   = (const float*)d_in[0];
    const float* inten = (const float*)d_in[1];
    const float* Wq  = (const float*)d_in[2];
    const float* bq  = (const float*)d_in[3];
    const float* Wk  = (const float*)d_in[4];
    const float* bk  = (const float*)d_in[5];
    const float* Wv  = (const float*)d_in[6];
    const float* bv  = (const float*)d_in[7];
    const float* Wo  = (const float*)d_in[8];
    const float* bo  = (const float*)d_in[9];
    const float* W1  = (const float*)d_in[10];
    const float* b1  = (const float*)d_in[11];
    const float* W2  = (const float*)d_in[12];
    const float* b2  = (const float*)d_in[13];
    const float* g1  = (const float*)d_in[14];
    const float* be1 = (const float*)d_in[15];
    const float* g2  = (const float*)d_in[16];
    const float* be2 = (const float*)d_in[17];
    float* out = (float*)d_out;

    char* ws = (char*)d_ws;
    const size_t MB = 1ull << 20;
    // layout (aliased; peak 216 MB):
    unsigned short* Xb  = (unsigned short*)(ws + 0);        // 16MB, dead after QKV
    unsigned short* Wqt = (unsigned short*)(ws + 16 * MB);  // 2MB
    unsigned short* Wkt = (unsigned short*)(ws + 18 * MB);
    unsigned short* Wvt = (unsigned short*)(ws + 20 * MB);
    unsigned short* Wot = (unsigned short*)(ws + 22 * MB);
    unsigned short* W1t = (unsigned short*)(ws + 24 * MB);  // 8MB
    unsigned short* W2t = (unsigned short*)(ws + 32 * MB);  // 8MB
    unsigned short* Qb  = (unsigned short*)(ws + 40 * MB);  // 16MB, dead after scores
    unsigned short* Kb  = (unsigned short*)(ws + 56 * MB);  // 16MB, dead after scores
    unsigned short* Vt  = (unsigned short*)(ws + 72 * MB);  // 16MB  [B][D][S]
    float*          Sc  = (float*)(ws + 88 * MB);           // 64MB, dead after softmax
    unsigned short* At  = (unsigned short*)(ws + 152 * MB); // 32MB, dead after attnV
    unsigned short* AVb = (unsigned short*)(ws + 0);        // 16MB (reuse Xb)
    float*          O1  = (float*)(ws + 40 * MB);           // 32MB (reuse Qb+Kb)
    float*          Hf  = (float*)(ws + 88 * MB);           // 32MB (reuse Sc)
    unsigned short* Hb  = (unsigned short*)(ws + 120 * MB); // 16MB (reuse Sc)
    unsigned short* F1  = (unsigned short*)(ws + 152 * MB); // 64MB (reuse At + fresh) -> 216MB
    float*          F2  = (float*)(ws + 40 * MB);           // 32MB (reuse O1)

    const dim3 blk(256);
    const dim3 tblk(32, 8);

    // casts
    cast_bf16_kernel<<<dim3(8192), blk, 0, stream>>>(
        (const float4*)X, (ushort4*)Xb, B_ * S_ * D_ / 4);
    transpose_cast_kernel<<<dim3(D_ / 32, D_ / 32), tblk, 0, stream>>>(Wq, Wqt, D_, D_);
    transpose_cast_kernel<<<dim3(D_ / 32, D_ / 32), tblk, 0, stream>>>(Wk, Wkt, D_, D_);
    transpose_cast_kernel<<<dim3(D_ / 32, D_ / 32), tblk, 0, stream>>>(Wv, Wvt, D_, D_);
    transpose_cast_kernel<<<dim3(D_ / 32, D_ / 32), tblk, 0, stream>>>(Wo, Wot, D_, D_);
    transpose_cast_kernel<<<dim3(DFF_ / 32, D_ / 32), tblk, 0, stream>>>(W1, W1t, D_, DFF_);
    transpose_cast_kernel<<<dim3(D_ / 32, DFF_ / 32), tblk, 0, stream>>>(W2, W2t, DFF_, D_);

    // Q, K (bf16 out, bias), V (bf16 out transposed -> Vt[B][D][S], bias)
    gemm_bt<1, 0, 0, 1><<<dim3(8, 64, 1), blk, 0, stream>>>(
        Xb, Wqt, Qb, bq, B_ * S_, D_, D_, 1.0f, 0, 0, 0, 1);
    gemm_bt<1, 0, 0, 1><<<dim3(8, 64, 1), blk, 0, stream>>>(
        Xb, Wkt, Kb, bk, B_ * S_, D_, D_, 1.0f, 0, 0, 0, 1);
    gemm_bt<1, 0, 1, 1><<<dim3(8, 64, 1), blk, 0, stream>>>(
        Xb, Wvt, Vt, bv, B_ * S_, D_, D_, 1.0f, 0, 0, 0, S_);

    // scores = Q @ K^T / 32  (fp32, batched)
    gemm_bt<0, 0, 0, 0><<<dim3(16, 16, 4), blk, 0, stream>>>(
        Qb, Kb, Sc, nullptr, S_, S_, D_, 0.03125f,
        (long long)S_ * D_, (long long)S_ * D_, (long long)S_ * S_, 1);

    // attn = softmax(scores) + intensity  (bf16)
    softmax_bias_kernel<<<dim3(B_ * S_), blk, 0, stream>>>(Sc, inten, At);

    // AV = attn @ V  (bf16, batched; Bt = Vt[B][D][S])
    gemm_bt<1, 0, 0, 0><<<dim3(8, 16, 4), blk, 0, stream>>>(
        At, Vt, AVb, nullptr, S_, D_, S_, 1.0f,
        (long long)S_ * S_, (long long)D_ * S_, (long long)S_ * D_, 1);

    // O1 = AV @ Wo + bo  (fp32)
    gemm_bt<0, 0, 0, 1><<<dim3(8, 64, 1), blk, 0, stream>>>(
        AVb, Wot, O1, bo, B_ * S_, D_, D_, 1.0f, 0, 0, 0, 1);

    // h = LN(O1 + X)  -> Hf (fp32) + Hb (bf16)
    ln_kernel<<<dim3(B_ * S_), blk, 0, stream>>>(O1, X, g1, be1, Hf, Hb);

    // F1 = leaky_relu(h @ W1 + b1)  (bf16)
    gemm_bt<1, 1, 0, 1><<<dim3(32, 64, 1), blk, 0, stream>>>(
        Hb, W1t, F1, b1, B_ * S_, DFF_, D_, 1.0f, 0, 0, 0, 1);

    // F2 = F1 @ W2 + b2  (fp32)
    gemm_bt<0, 0, 0, 1><<<dim3(8, 64, 1), blk, 0, stream>>>(
        F1, W2t, F2, b2, B_ * S_, D_, DFF_, 1.0f, 0, 0, 0, 1);

    // out = LN(F2 + h)
    ln_kernel<<<dim3(B_ * S_), blk, 0, stream>>>(F2, Hf, g2, be2, out, nullptr);
}

// Round 2
// 701.247 us; speedup vs baseline: 1.0300x; 1.0300x over previous
//
#include <hip/hip_runtime.h>

#define B_   4
#define S_   2048
#define D_   1024
#define DFF_ 4096

typedef __attribute__((ext_vector_type(8))) short short8;
typedef __attribute__((ext_vector_type(4))) float floatx4;

__device__ __forceinline__ unsigned short f2b(float f) {
    unsigned int u = __float_as_uint(f);
    unsigned int r = (u + 0x7fffu + ((u >> 16) & 1u)) >> 16;
    return (unsigned short)r;
}

// XCD-aware swizzle: blocks sharing an A row-tile (same by) land on one XCD.
// Assumes round-robin linear-id -> XCD. Requires gy % 8 == 0 (else identity).
__device__ __forceinline__ void swizzle_xy(int gx, int gy, int& bx, int& by) {
    if ((gy & 7) == 0) {
        const int linear = by * gx + bx;
        const int xcd = linear & 7;
        const int slot = linear >> 3;
        const int r = slot / gx;
        by = xcd * (gy >> 3) + r;
        bx = slot - r * gx;
    }
}

// ---------------------------------------------------------------------------
// cast fp32 -> bf16, vectorized (float4 in, ushort4 out)
// ---------------------------------------------------------------------------
__global__ __launch_bounds__(256) void cast_bf16_kernel(
    const float4* __restrict__ src, ushort4* __restrict__ dst, int n4)
{
    int i = blockIdx.x * 256 + threadIdx.x;
    if (i < n4) {
        float4 f = src[i];
        ushort4 u;
        u.x = f2b(f.x); u.y = f2b(f.y); u.z = f2b(f.z); u.w = f2b(f.w);
        dst[i] = u;
    }
}

// ---------------------------------------------------------------------------
// transpose + cast: W [K,N] fp32 row-major -> Wt [N,K] bf16 row-major
// ---------------------------------------------------------------------------
__global__ __launch_bounds__(256) void transpose_cast_kernel(
    const float* __restrict__ W, unsigned short* __restrict__ Wt, int K, int N)
{
    __shared__ float tile[32][33];
    const int tx = threadIdx.x;
    const int ty = threadIdx.y;
    const int bx = blockIdx.x * 32;
    const int by = blockIdx.y * 32;
#pragma unroll
    for (int j = 0; j < 32; j += 8)
        tile[ty + j][tx] = W[(long long)(by + ty + j) * N + bx + tx];
    __syncthreads();
#pragma unroll
    for (int j = 0; j < 32; j += 8)
        Wt[(long long)(bx + ty + j) * K + by + tx] = f2b(tile[tx][ty + j]);
}

// ---------------------------------------------------------------------------
// GEMM 128x128 tile, BK=32, 4 waves (64x64 each), m97-style staging.
// C[M,N](+z*sC) = act( scale * A(+z*sA) @ Bt(+z*sB)^T + bias )
// ---------------------------------------------------------------------------
template <int OUT_BF16, int ACT_LEAKY, int HAS_BIAS>
__global__ __launch_bounds__(256) void gemm_bt(
    const unsigned short* __restrict__ A,
    const unsigned short* __restrict__ Bt,
    void* __restrict__ Cptr,
    const float* __restrict__ bias,
    int M, int N, int K, float scale,
    long long sA, long long sB, long long sC)
{
    __shared__ unsigned short As[128 * 32];
    __shared__ unsigned short Bs[128 * 32];

    const int tid  = threadIdx.x;
    const int lane = tid & 63;
    const int wave = tid >> 6;
    const int z    = blockIdx.z;

    A  += (long long)z * sA;
    Bt += (long long)z * sB;

    int bx = blockIdx.x, by = blockIdx.y;
    swizzle_xy(gridDim.x, gridDim.y, bx, by);
    const int m0 = by * 128;
    const int n0 = bx * 128;

    const int ra = tid >> 2;
    const int ca = (tid & 3) * 8;
    const unsigned short* gA = A  + (long long)(m0 + ra) * K + ca;
    const unsigned short* gB = Bt + (long long)(n0 + ra) * K + ca;
    const long long pass2 = 64LL * K;

    unsigned short* lA = &As[wave * 512];
    unsigned short* lB = &Bs[wave * 512];

    floatx4 acc[4][4];
#pragma unroll
    for (int i = 0; i < 4; i++)
#pragma unroll
        for (int j = 0; j < 4; j++) acc[i][j] = floatx4{0.f, 0.f, 0.f, 0.f};

    const int wr = (wave >> 1) * 64;
    const int wc = (wave & 1) * 64;
    const int fr = lane & 15;
    const int fk = (lane >> 4) * 8;

    for (int k0 = 0; k0 < K; k0 += 32) {
        __syncthreads();
        __builtin_amdgcn_global_load_lds(
            (const __attribute__((address_space(1))) void*)(gA + k0),
            (__attribute__((address_space(3))) void*)lA, 16, 0, 0);
        __builtin_amdgcn_global_load_lds(
            (const __attribute__((address_space(1))) void*)(gA + k0 + pass2),
            (__attribute__((address_space(3))) void*)(lA + 2048), 16, 0, 0);
        __builtin_amdgcn_global_load_lds(
            (const __attribute__((address_space(1))) void*)(gB + k0),
            (__attribute__((address_space(3))) void*)lB, 16, 0, 0);
        __builtin_amdgcn_global_load_lds(
            (const __attribute__((address_space(1))) void*)(gB + k0 + pass2),
            (__attribute__((address_space(3))) void*)(lB + 2048), 16, 0, 0);
        __syncthreads();

        short8 af[4], bfr[4];
#pragma unroll
        for (int mi = 0; mi < 4; mi++)
            af[mi] = *(const short8*)&As[(wr + mi * 16 + fr) * 32 + fk];
#pragma unroll
        for (int ni = 0; ni < 4; ni++)
            bfr[ni] = *(const short8*)&Bs[(wc + ni * 16 + fr) * 32 + fk];

#pragma unroll
        for (int mi = 0; mi < 4; mi++)
#pragma unroll
            for (int ni = 0; ni < 4; ni++)
                acc[mi][ni] = __builtin_amdgcn_mfma_f32_16x16x32_bf16(
                    af[mi], bfr[ni], acc[mi][ni], 0, 0, 0);
    }

    const int cr = (lane >> 4) * 4;
    const int cc = lane & 15;
    float* Cf = (float*)Cptr;
    unsigned short* Cb = (unsigned short*)Cptr;

#pragma unroll
    for (int mi = 0; mi < 4; mi++) {
#pragma unroll
        for (int ni = 0; ni < 4; ni++) {
            const int col = n0 + wc + ni * 16 + cc;
            const float bv = HAS_BIAS ? bias[col] : 0.0f;
#pragma unroll
            for (int r = 0; r < 4; r++) {
                const int row = m0 + wr + mi * 16 + cr + r;
                float v = acc[mi][ni][r] * scale + bv;
                if (ACT_LEAKY) v = (v > 0.0f) ? v : 0.01f * v;
                const long long idx = (long long)z * sC + (long long)row * N + col;
                if (OUT_BF16) Cb[idx] = f2b(v); else Cf[idx] = v;
            }
        }
    }
}

// ---------------------------------------------------------------------------
// Fused QKV GEMM: A[8192,1024] @ Wqkvt[3072,1024]^T. Epilogue routes:
// seg 0 -> Qb[row,c] bf16, seg 1 -> Kb[row,c] bf16, seg 2 -> Vt[b][c][s] bf16
// ---------------------------------------------------------------------------
__global__ __launch_bounds__(256) void gemm_qkv(
    const unsigned short* __restrict__ A,
    const unsigned short* __restrict__ Bt,
    unsigned short* __restrict__ Qb,
    unsigned short* __restrict__ Kb,
    unsigned short* __restrict__ Vt,
    const float* __restrict__ bq,
    const float* __restrict__ bk,
    const float* __restrict__ bv)
{
    const int K = D_;
    __shared__ unsigned short As[128 * 32];
    __shared__ unsigned short Bs[128 * 32];

    const int tid  = threadIdx.x;
    const int lane = tid & 63;
    const int wave = tid >> 6;

    int bx = blockIdx.x, by = blockIdx.y;
    swizzle_xy(gridDim.x, gridDim.y, bx, by);
    const int m0 = by * 128;
    const int n0 = bx * 128;

    const int ra = tid >> 2;
    const int ca = (tid & 3) * 8;
    const unsigned short* gA = A  + (long long)(m0 + ra) * K + ca;
    const unsigned short* gB = Bt + (long long)(n0 + ra) * K + ca;
    const long long pass2 = 64LL * K;

    unsigned short* lA = &As[wave * 512];
    unsigned short* lB = &Bs[wave * 512];

    floatx4 acc[4][4];
#pragma unroll
    for (int i = 0; i < 4; i++)
#pragma unroll
        for (int j = 0; j < 4; j++) acc[i][j] = floatx4{0.f, 0.f, 0.f, 0.f};

    const int wr = (wave >> 1) * 64;
    const int wc = (wave & 1) * 64;
    const int fr = lane & 15;
    const int fk = (lane >> 4) * 8;

    for (int k0 = 0; k0 < K; k0 += 32) {
        __syncthreads();
        __builtin_amdgcn_global_load_lds(
            (const __attribute__((address_space(1))) void*)(gA + k0),
            (__attribute__((address_space(3))) void*)lA, 16, 0, 0);
        __builtin_amdgcn_global_load_lds(
            (const __attribute__((address_space(1))) void*)(gA + k0 + pass2),
            (__attribute__((address_space(3))) void*)(lA + 2048), 16, 0, 0);
        __builtin_amdgcn_global_load_lds(
            (const __attribute__((address_space(1))) void*)(gB + k0),
            (__attribute__((address_space(3))) void*)lB, 16, 0, 0);
        __builtin_amdgcn_global_load_lds(
            (const __attribute__((address_space(1))) void*)(gB + k0 + pass2),
            (__attribute__((address_space(3))) void*)(lB + 2048), 16, 0, 0);
        __syncthreads();

        short8 af[4], bfr[4];
#pragma unroll
        for (int mi = 0; mi < 4; mi++)
            af[mi] = *(const short8*)&As[(wr + mi * 16 + fr) * 32 + fk];
#pragma unroll
        for (int ni = 0; ni < 4; ni++)
            bfr[ni] = *(const short8*)&Bs[(wc + ni * 16 + fr) * 32 + fk];

#pragma unroll
        for (int mi = 0; mi < 4; mi++)
#pragma unroll
            for (int ni = 0; ni < 4; ni++)
                acc[mi][ni] = __builtin_amdgcn_mfma_f32_16x16x32_bf16(
                    af[mi], bfr[ni], acc[mi][ni], 0, 0, 0);
    }

    const int cr = (lane >> 4) * 4;
    const int cc = lane & 15;

#pragma unroll
    for (int mi = 0; mi < 4; mi++) {
#pragma unroll
        for (int ni = 0; ni < 4; ni++) {
            const int col = n0 + wc + ni * 16 + cc;   // 0..3071
            const int seg = col >> 10;                // uniform within this ni
            const int c = col & 1023;
            const float* bp = (seg == 0) ? bq : ((seg == 1) ? bk : bv);
            const float bval = bp[c];
#pragma unroll
            for (int r = 0; r < 4; r++) {
                const int row = m0 + wr + mi * 16 + cr + r;
                const unsigned short o = f2b(acc[mi][ni][r] + bval);
                if (seg == 0) {
                    Qb[(long long)row * D_ + c] = o;
                } else if (seg == 1) {
                    Kb[(long long)row * D_ + c] = o;
                } else {
                    const int b = row >> 11;          // row / S_
                    const int s = row & (S_ - 1);
                    Vt[((long long)b * D_ + c) * S_ + s] = o;
                }
            }
        }
    }
}

// ---------------------------------------------------------------------------
// GEMM 128x64 tile, BK=32, 2 waves (each 64 rows x 64 cols), 128 threads.
// For thin-N GEMMs where the 128x128 grid would be only 2 blocks/CU.
// ---------------------------------------------------------------------------
template <int OUT_BF16, int HAS_BIAS>
__global__ __launch_bounds__(128) void gemm_bt_n64(
    const unsigned short* __restrict__ A,
    const unsigned short* __restrict__ Bt,
    void* __restrict__ Cptr,
    const float* __restrict__ bias,
    int M, int N, int K, float scale,
    long long sA, long long sB, long long sC)
{
    __shared__ unsigned short As[128 * 32];
    __shared__ unsigned short Bs[64 * 32];

    const int tid  = threadIdx.x;   // 0..127
    const int lane = tid & 63;
    const int wave = tid >> 6;      // 0..1
    const int z    = blockIdx.z;

    A  += (long long)z * sA;
    Bt += (long long)z * sB;

    int bx = blockIdx.x, by = blockIdx.y;
    swizzle_xy(gridDim.x, gridDim.y, bx, by);
    const int m0 = by * 128;
    const int n0 = bx * 64;

    const int ra = tid >> 2;        // 0..31 (32 rows per staging pass)
    const int ca = (tid & 3) * 8;
    const unsigned short* gA = A  + (long long)(m0 + ra) * K + ca;
    const unsigned short* gB = Bt + (long long)(n0 + ra) * K + ca;
    const long long rstep = 32LL * K;

    unsigned short* lA = &As[wave * 512];
    unsigned short* lB = &Bs[wave * 512];

    floatx4 acc[4][4];
#pragma unroll
    for (int i = 0; i < 4; i++)
#pragma unroll
        for (int j = 0; j < 4; j++) acc[i][j] = floatx4{0.f, 0.f, 0.f, 0.f};

    const int wr = wave * 64;
    const int fr = lane & 15;
    const int fk = (lane >> 4) * 8;

    for (int k0 = 0; k0 < K; k0 += 32) {
        __syncthreads();
#pragma unroll
        for (int p = 0; p < 4; p++)
            __builtin_amdgcn_global_load_lds(
                (const __attribute__((address_space(1))) void*)(gA + k0 + p * rstep),
                (__attribute__((address_space(3))) void*)(lA + p * 1024), 16, 0, 0);
#pragma unroll
        for (int p = 0; p < 2; p++)
            __builtin_amdgcn_global_load_lds(
                (const __attribute__((address_space(1))) void*)(gB + k0 + p * rstep),
                (__attribute__((address_space(3))) void*)(lB + p * 1024), 16, 0, 0);
        __syncthreads();

        short8 af[4], bfr[4];
#pragma unroll
        for (int mi = 0; mi < 4; mi++)
            af[mi] = *(const short8*)&As[(wr + mi * 16 + fr) * 32 + fk];
#pragma unroll
        for (int ni = 0; ni < 4; ni++)
            bfr[ni] = *(const short8*)&Bs[(ni * 16 + fr) * 32 + fk];

#pragma unroll
        for (int mi = 0; mi < 4; mi++)
#pragma unroll
            for (int ni = 0; ni < 4; ni++)
                acc[mi][ni] = __builtin_amdgcn_mfma_f32_16x16x32_bf16(
                    af[mi], bfr[ni], acc[mi][ni], 0, 0, 0);
    }

    const int cr = (lane >> 4) * 4;
    const int cc = lane & 15;
    float* Cf = (float*)Cptr;
    unsigned short* Cb = (unsigned short*)Cptr;

#pragma unroll
    for (int mi = 0; mi < 4; mi++) {
#pragma unroll
        for (int ni = 0; ni < 4; ni++) {
            const int col = n0 + ni * 16 + cc;
            const float bval = HAS_BIAS ? bias[col] : 0.0f;
#pragma unroll
            for (int r = 0; r < 4; r++) {
                const int row = m0 + wr + mi * 16 + cr + r;
                float v = acc[mi][ni][r] * scale + bval;
                const long long idx = (long long)z * sC + (long long)row * N + col;
                if (OUT_BF16) Cb[idx] = f2b(v); else Cf[idx] = v;
            }
        }
    }
}

// ---------------------------------------------------------------------------
// softmax over rows of scores [B*S, S] + intensity, write bf16 attn
// ---------------------------------------------------------------------------
__global__ __launch_bounds__(256) void softmax_bias_kernel(
    const float* __restrict__ scores, const float* __restrict__ intensity,
    unsigned short* __restrict__ attn)
{
    __shared__ float red[8];
    const long long row = blockIdx.x;
    const int tid = threadIdx.x;
    const float4* s4 = (const float4*)(scores + row * S_);
    const float4* i4 = (const float4*)(intensity + row * S_);
    ushort4* dst = (ushort4*)(attn + row * S_);

    float vv[8];
    {
        float4 a = s4[tid], b = s4[tid + 256];
        vv[0] = a.x; vv[1] = a.y; vv[2] = a.z; vv[3] = a.w;
        vv[4] = b.x; vv[5] = b.y; vv[6] = b.z; vv[7] = b.w;
    }

    float mx = vv[0];
#pragma unroll
    for (int i = 1; i < 8; i++) mx = fmaxf(mx, vv[i]);
#pragma unroll
    for (int o = 32; o > 0; o >>= 1) mx = fmaxf(mx, __shfl_xor(mx, o));
    if ((tid & 63) == 0) red[tid >> 6] = mx;
    __syncthreads();
    mx = fmaxf(fmaxf(red[0], red[1]), fmaxf(red[2], red[3]));

    float e[8];
    float sum = 0.f;
#pragma unroll
    for (int i = 0; i < 8; i++) { e[i] = __expf(vv[i] - mx); sum += e[i]; }
#pragma unroll
    for (int o = 32; o > 0; o >>= 1) sum += __shfl_xor(sum, o);
    if ((tid & 63) == 0) red[4 + (tid >> 6)] = sum;
    __syncthreads();
    sum = red[4] + red[5] + red[6] + red[7];
    const float rs = 1.0f / sum;

#pragma unroll
    for (int i = 0; i < 2; i++) {
        float4 iv = i4[tid + 256 * i];
        ushort4 o;
        o.x = f2b(e[4 * i + 0] * rs + iv.x);
        o.y = f2b(e[4 * i + 1] * rs + iv.y);
        o.z = f2b(e[4 * i + 2] * rs + iv.z);
        o.w = f2b(e[4 * i + 3] * rs + iv.w);
        dst[tid + 256 * i] = o;
    }
}

// ---------------------------------------------------------------------------
// LayerNorm(x + resid) * g + b ; writes fp32 out and optional bf16 out
// ---------------------------------------------------------------------------
__global__ __launch_bounds__(256) void ln_kernel(
    const float* __restrict__ x, const float* __restrict__ resid,
    const float* __restrict__ g, const float* __restrict__ b,
    float* __restrict__ out_f, unsigned short* __restrict__ out_b)
{
    __shared__ float red[8];
    const long long row = blockIdx.x;
    const int tid = threadIdx.x;
    const float4 xv = ((const float4*)(x + row * D_))[tid];
    const float4 rv = ((const float4*)(resid + row * D_))[tid];
    float v0 = xv.x + rv.x, v1 = xv.y + rv.y, v2 = xv.z + rv.z, v3 = xv.w + rv.w;

    float s = v0 + v1 + v2 + v3;
#pragma unroll
    for (int o = 32; o > 0; o >>= 1) s += __shfl_xor(s, o);
    if ((tid & 63) == 0) red[tid >> 6] = s;
    __syncthreads();
    const float mean = (red[0] + red[1] + red[2] + red[3]) * (1.0f / D_);

    const float d0 = v0 - mean, d1 = v1 - mean, d2 = v2 - mean, d3 = v3 - mean;
    float q = d0 * d0 + d1 * d1 + d2 * d2 + d3 * d3;
#pragma unroll
    for (int o = 32; o > 0; o >>= 1) q += __shfl_xor(q, o);
    if ((tid & 63) == 0) red[4 + (tid >> 6)] = q;
    __syncthreads();
    const float var = (red[4] + red[5] + red[6] + red[7]) * (1.0f / D_);
    const float inv = rsqrtf(var + 1e-6f);

    const float4 gv = ((const float4*)g)[tid];
    const float4 bv = ((const float4*)b)[tid];
    const float o0 = d0 * inv * gv.x + bv.x;
    const float o1 = d1 * inv * gv.y + bv.y;
    const float o2 = d2 * inv * gv.z + bv.z;
    const float o3 = d3 * inv * gv.w + bv.w;

    ((float4*)(out_f + row * D_))[tid] = float4{o0, o1, o2, o3};
    if (out_b) {
        ushort4 u; u.x = f2b(o0); u.y = f2b(o1); u.z = f2b(o2); u.w = f2b(o3);
        ((ushort4*)(out_b + row * D_))[tid] = u;
    }
}

// ---------------------------------------------------------------------------
extern "C" void kernel_launch(void* const* d_in, const int* in_sizes, int n_in,
                              void* d_out, int out_size, void* d_ws, size_t ws_size,
                              hipStream_t stream)
{
    const float* X   = (const float*)d_in[0];
    const float* inten = (const float*)d_in[1];
    const float* Wq  = (const float*)d_in[2];
    const float* bq  = (const float*)d_in[3];
    const float* Wk  = (const float*)d_in[4];
    const float* bk  = (const float*)d_in[5];
    const float* Wv  = (const float*)d_in[6];
    const float* bv  = (const float*)d_in[7];
    const float* Wo  = (const float*)d_in[8];
    const float* bo  = (const float*)d_in[9];
    const float* W1  = (const float*)d_in[10];
    const float* b1  = (const float*)d_in[11];
    const float* W2  = (const float*)d_in[12];
    const float* b2  = (const float*)d_in[13];
    const float* g1  = (const float*)d_in[14];
    const float* be1 = (const float*)d_in[15];
    const float* g2  = (const float*)d_in[16];
    const float* be2 = (const float*)d_in[17];
    float* out = (float*)d_out;

    char* ws = (char*)d_ws;
    const size_t MB = 1ull << 20;
    unsigned short* Xb   = (unsigned short*)(ws + 0);        // 16MB, dead after QKV
    unsigned short* Wqkv = (unsigned short*)(ws + 16 * MB);  // 6MB [3072][1024]
    unsigned short* Wot  = (unsigned short*)(ws + 22 * MB);  // 2MB
    unsigned short* W1t  = (unsigned short*)(ws + 24 * MB);  // 8MB
    unsigned short* W2t  = (unsigned short*)(ws + 32 * MB);  // 8MB
    unsigned short* Qb   = (unsigned short*)(ws + 40 * MB);  // 16MB
    unsigned short* Kb   = (unsigned short*)(ws + 56 * MB);  // 16MB
    unsigned short* Vt   = (unsigned short*)(ws + 72 * MB);  // 16MB [B][D][S]
    float*          Sc   = (float*)(ws + 88 * MB);           // 64MB
    unsigned short* At   = (unsigned short*)(ws + 152 * MB); // 32MB
    unsigned short* AVb  = (unsigned short*)(ws + 0);        // 16MB (reuse Xb)
    float*          O1   = (float*)(ws + 40 * MB);           // 32MB (reuse Qb+Kb)
    float*          Hf   = (float*)(ws + 88 * MB);           // 32MB (reuse Sc)
    unsigned short* Hb   = (unsigned short*)(ws + 120 * MB); // 16MB (reuse Sc)
    unsigned short* F1   = (unsigned short*)(ws + 152 * MB); // 64MB
    float*          F2   = (float*)(ws + 40 * MB);           // 32MB (reuse O1)

    const dim3 blk(256);
    const dim3 blk128(128);
    const dim3 tblk(32, 8);

    // casts / weight transposes
    cast_bf16_kernel<<<dim3(8192), blk, 0, stream>>>(
        (const float4*)X, (ushort4*)Xb, B_ * S_ * D_ / 4);
    transpose_cast_kernel<<<dim3(D_ / 32, D_ / 32), tblk, 0, stream>>>(
        Wq, Wqkv, D_, D_);
    transpose_cast_kernel<<<dim3(D_ / 32, D_ / 32), tblk, 0, stream>>>(
        Wk, Wqkv + 1024 * 1024, D_, D_);
    transpose_cast_kernel<<<dim3(D_ / 32, D_ / 32), tblk, 0, stream>>>(
        Wv, Wqkv + 2048 * 1024, D_, D_);
    transpose_cast_kernel<<<dim3(D_ / 32, D_ / 32), tblk, 0, stream>>>(Wo, Wot, D_, D_);
    transpose_cast_kernel<<<dim3(DFF_ / 32, D_ / 32), tblk, 0, stream>>>(W1, W1t, D_, DFF_);
    transpose_cast_kernel<<<dim3(D_ / 32, DFF_ / 32), tblk, 0, stream>>>(W2, W2t, DFF_, D_);

    // fused QKV: [8192,1024] @ [3072,1024]^T, grid 24x64 = 1536 blocks
    gemm_qkv<<<dim3(24, 64), blk, 0, stream>>>(Xb, Wqkv, Qb, Kb, Vt, bq, bk, bv);

    // scores = Q @ K^T / 32  (fp32, batched), grid 16x16x4 = 1024 blocks
    gemm_bt<0, 0, 0><<<dim3(16, 16, 4), blk, 0, stream>>>(
        Qb, Kb, Sc, nullptr, S_, S_, D_, 0.03125f,
        (long long)S_ * D_, (long long)S_ * D_, (long long)S_ * S_);

    // attn = softmax(scores) + intensity  (bf16)
    softmax_bias_kernel<<<dim3(B_ * S_), blk, 0, stream>>>(Sc, inten, At);

    // AV = attn @ V  (bf16, batched; Bt = Vt), grid 16x16x4 = 1024 blocks
    gemm_bt_n64<1, 0><<<dim3(16, 16, 4), blk128, 0, stream>>>(
        At, Vt, AVb, nullptr, S_, D_, S_, 1.0f,
        (long long)S_ * S_, (long long)D_ * S_, (long long)S_ * D_);

    // O1 = AV @ Wo + bo  (fp32), grid 16x64 = 1024 blocks
    gemm_bt_n64<0, 1><<<dim3(16, 64), blk128, 0, stream>>>(
        AVb, Wot, O1, bo, B_ * S_, D_, D_, 1.0f, 0, 0, 0);

    // h = LN(O1 + X)  -> Hf (fp32) + Hb (bf16)
    ln_kernel<<<dim3(B_ * S_), blk, 0, stream>>>(O1, X, g1, be1, Hf, Hb);

    // F1 = leaky_relu(h @ W1 + b1)  (bf16), grid 32x64 = 2048 blocks
    gemm_bt<1, 1, 1><<<dim3(32, 64), blk, 0, stream>>>(
        Hb, W1t, F1, b1, B_ * S_, DFF_, D_, 1.0f, 0, 0, 0);

    // F2 = F1 @ W2 + b2  (fp32), grid 16x64 = 1024 blocks
    gemm_bt_n64<0, 1><<<dim3(16, 64), blk128, 0, stream>>>(
        F1, W2t, F2, b2, B_ * S_, D_, DFF_, 1.0f, 0, 0, 0);

    // out = LN(F2 + h)
    ln_kernel<<<dim3(B_ * S_), blk, 0, stream>>>(F2, Hf, g2, be2, out, nullptr);
}

// Round 3
// 693.531 us; speedup vs baseline: 1.0415x; 1.0111x over previous
//
#include <hip/hip_runtime.h>

#define B_   4
#define S_   2048
#define D_   1024
#define DFF_ 4096

typedef __attribute__((ext_vector_type(8))) short short8;
typedef __attribute__((ext_vector_type(4))) float floatx4;

__device__ __forceinline__ unsigned short f2b(float f) {
    unsigned int u = __float_as_uint(f);
    unsigned int r = (u + 0x7fffu + ((u >> 16) & 1u)) >> 16;
    return (unsigned short)r;
}

// XCD-aware swizzle: blocks sharing an A row-tile (same by) land on one XCD.
__device__ __forceinline__ void swizzle_xy(int gx, int gy, int& bx, int& by) {
    if ((gy & 7) == 0) {
        const int linear = by * gx + bx;
        const int xcd = linear & 7;
        const int slot = linear >> 3;
        const int r = slot / gx;
        by = xcd * (gy >> 3) + r;
        bx = slot - r * gx;
    }
}

// ---------------------------------------------------------------------------
__global__ __launch_bounds__(256) void cast_bf16_kernel(
    const float4* __restrict__ src, ushort4* __restrict__ dst, int n4)
{
    int i = blockIdx.x * 256 + threadIdx.x;
    if (i < n4) {
        float4 f = src[i];
        ushort4 u;
        u.x = f2b(f.x); u.y = f2b(f.y); u.z = f2b(f.z); u.w = f2b(f.w);
        dst[i] = u;
    }
}

// ---------------------------------------------------------------------------
__global__ __launch_bounds__(256) void transpose_cast_kernel(
    const float* __restrict__ W, unsigned short* __restrict__ Wt, int K, int N)
{
    __shared__ float tile[32][33];
    const int tx = threadIdx.x;
    const int ty = threadIdx.y;
    const int bx = blockIdx.x * 32;
    const int by = blockIdx.y * 32;
#pragma unroll
    for (int j = 0; j < 32; j += 8)
        tile[ty + j][tx] = W[(long long)(by + ty + j) * N + bx + tx];
    __syncthreads();
#pragma unroll
    for (int j = 0; j < 32; j += 8)
        Wt[(long long)(bx + ty + j) * K + by + tx] = f2b(tile[tx][ty + j]);
}

// ---------------------------------------------------------------------------
// GEMM 128x128 tile, BK=32, 4 waves (64x64 each), m97-style staging.
// C[M,N](+z*sC) = act( scale * A(+z*sA) @ Bt(+z*sB)^T + bias )
// ---------------------------------------------------------------------------
template <int OUT_BF16, int ACT_LEAKY, int HAS_BIAS>
__global__ __launch_bounds__(256) void gemm_bt(
    const unsigned short* __restrict__ A,
    const unsigned short* __restrict__ Bt,
    void* __restrict__ Cptr,
    const float* __restrict__ bias,
    int M, int N, int K, float scale,
    long long sA, long long sB, long long sC)
{
    __shared__ unsigned short As[128 * 32];
    __shared__ unsigned short Bs[128 * 32];

    const int tid  = threadIdx.x;
    const int lane = tid & 63;
    const int wave = tid >> 6;
    const int z    = blockIdx.z;

    A  += (long long)z * sA;
    Bt += (long long)z * sB;

    int bx = blockIdx.x, by = blockIdx.y;
    swizzle_xy(gridDim.x, gridDim.y, bx, by);
    const int m0 = by * 128;
    const int n0 = bx * 128;

    const int ra = tid >> 2;
    const int ca = (tid & 3) * 8;
    const unsigned short* gA = A  + (long long)(m0 + ra) * K + ca;
    const unsigned short* gB = Bt + (long long)(n0 + ra) * K + ca;
    const long long pass2 = 64LL * K;

    unsigned short* lA = &As[wave * 512];
    unsigned short* lB = &Bs[wave * 512];

    floatx4 acc[4][4];
#pragma unroll
    for (int i = 0; i < 4; i++)
#pragma unroll
        for (int j = 0; j < 4; j++) acc[i][j] = floatx4{0.f, 0.f, 0.f, 0.f};

    const int wr = (wave >> 1) * 64;
    const int wc = (wave & 1) * 64;
    const int fr = lane & 15;
    const int fk = (lane >> 4) * 8;

    for (int k0 = 0; k0 < K; k0 += 32) {
        __syncthreads();
        __builtin_amdgcn_global_load_lds(
            (const __attribute__((address_space(1))) void*)(gA + k0),
            (__attribute__((address_space(3))) void*)lA, 16, 0, 0);
        __builtin_amdgcn_global_load_lds(
            (const __attribute__((address_space(1))) void*)(gA + k0 + pass2),
            (__attribute__((address_space(3))) void*)(lA + 2048), 16, 0, 0);
        __builtin_amdgcn_global_load_lds(
            (const __attribute__((address_space(1))) void*)(gB + k0),
            (__attribute__((address_space(3))) void*)lB, 16, 0, 0);
        __builtin_amdgcn_global_load_lds(
            (const __attribute__((address_space(1))) void*)(gB + k0 + pass2),
            (__attribute__((address_space(3))) void*)(lB + 2048), 16, 0, 0);
        __syncthreads();

        short8 af[4], bfr[4];
#pragma unroll
        for (int mi = 0; mi < 4; mi++)
            af[mi] = *(const short8*)&As[(wr + mi * 16 + fr) * 32 + fk];
#pragma unroll
        for (int ni = 0; ni < 4; ni++)
            bfr[ni] = *(const short8*)&Bs[(wc + ni * 16 + fr) * 32 + fk];

#pragma unroll
        for (int mi = 0; mi < 4; mi++)
#pragma unroll
            for (int ni = 0; ni < 4; ni++)
                acc[mi][ni] = __builtin_amdgcn_mfma_f32_16x16x32_bf16(
                    af[mi], bfr[ni], acc[mi][ni], 0, 0, 0);
    }

    const int cr = (lane >> 4) * 4;
    const int cc = lane & 15;
    float* Cf = (float*)Cptr;
    unsigned short* Cb = (unsigned short*)Cptr;

#pragma unroll
    for (int mi = 0; mi < 4; mi++) {
#pragma unroll
        for (int ni = 0; ni < 4; ni++) {
            const int col = n0 + wc + ni * 16 + cc;
            const float bv = HAS_BIAS ? bias[col] : 0.0f;
#pragma unroll
            for (int r = 0; r < 4; r++) {
                const int row = m0 + wr + mi * 16 + cr + r;
                float v = acc[mi][ni][r] * scale + bv;
                if (ACT_LEAKY) v = (v > 0.0f) ? v : 0.01f * v;
                const long long idx = (long long)z * sC + (long long)row * N + col;
                if (OUT_BF16) Cb[idx] = f2b(v); else Cf[idx] = v;
            }
        }
    }
}

// ---------------------------------------------------------------------------
// Split-K GEMM: 128x128 tile, 4 waves. blockIdx.z = b * NK + ks.
// Partial P[(ks*nb + b)][M][N] (fp32) = A[b] (rows ldA) [ks*Kslice ..] @ Bt^T
// ---------------------------------------------------------------------------
template <int NK>
__global__ __launch_bounds__(256) void gemm_bt_sk(
    const unsigned short* __restrict__ A,
    const unsigned short* __restrict__ Bt,
    float* __restrict__ P,
    int M, int N, int Kslice, int ldA, int ldB,
    long long sA, long long sB)
{
    __shared__ unsigned short As[128 * 32];
    __shared__ unsigned short Bs[128 * 32];

    const int tid  = threadIdx.x;
    const int lane = tid & 63;
    const int wave = tid >> 6;
    const int z    = blockIdx.z;
    const int ks   = z % NK;
    const int b    = z / NK;
    const int nb   = gridDim.z / NK;

    A  += (long long)b * sA + (long long)ks * Kslice;
    Bt += (long long)b * sB + (long long)ks * Kslice;
    P  += ((long long)ks * nb + b) * (long long)M * N;

    int bx = blockIdx.x, by = blockIdx.y;
    swizzle_xy(gridDim.x, gridDim.y, bx, by);
    const int m0 = by * 128;
    const int n0 = bx * 128;

    const int ra = tid >> 2;
    const int ca = (tid & 3) * 8;
    const unsigned short* gA = A  + (long long)(m0 + ra) * ldA + ca;
    const unsigned short* gB = Bt + (long long)(n0 + ra) * ldB + ca;
    const long long pA2 = 64LL * ldA;
    const long long pB2 = 64LL * ldB;

    unsigned short* lA = &As[wave * 512];
    unsigned short* lB = &Bs[wave * 512];

    floatx4 acc[4][4];
#pragma unroll
    for (int i = 0; i < 4; i++)
#pragma unroll
        for (int j = 0; j < 4; j++) acc[i][j] = floatx4{0.f, 0.f, 0.f, 0.f};

    const int wr = (wave >> 1) * 64;
    const int wc = (wave & 1) * 64;
    const int fr = lane & 15;
    const int fk = (lane >> 4) * 8;

    for (int k0 = 0; k0 < Kslice; k0 += 32) {
        __syncthreads();
        __builtin_amdgcn_global_load_lds(
            (const __attribute__((address_space(1))) void*)(gA + k0),
            (__attribute__((address_space(3))) void*)lA, 16, 0, 0);
        __builtin_amdgcn_global_load_lds(
            (const __attribute__((address_space(1))) void*)(gA + k0 + pA2),
            (__attribute__((address_space(3))) void*)(lA + 2048), 16, 0, 0);
        __builtin_amdgcn_global_load_lds(
            (const __attribute__((address_space(1))) void*)(gB + k0),
            (__attribute__((address_space(3))) void*)lB, 16, 0, 0);
        __builtin_amdgcn_global_load_lds(
            (const __attribute__((address_space(1))) void*)(gB + k0 + pB2),
            (__attribute__((address_space(3))) void*)(lB + 2048), 16, 0, 0);
        __syncthreads();

        short8 af[4], bfr[4];
#pragma unroll
        for (int mi = 0; mi < 4; mi++)
            af[mi] = *(const short8*)&As[(wr + mi * 16 + fr) * 32 + fk];
#pragma unroll
        for (int ni = 0; ni < 4; ni++)
            bfr[ni] = *(const short8*)&Bs[(wc + ni * 16 + fr) * 32 + fk];

#pragma unroll
        for (int mi = 0; mi < 4; mi++)
#pragma unroll
            for (int ni = 0; ni < 4; ni++)
                acc[mi][ni] = __builtin_amdgcn_mfma_f32_16x16x32_bf16(
                    af[mi], bfr[ni], acc[mi][ni], 0, 0, 0);
    }

    const int cr = (lane >> 4) * 4;
    const int cc = lane & 15;

#pragma unroll
    for (int mi = 0; mi < 4; mi++) {
#pragma unroll
        for (int ni = 0; ni < 4; ni++) {
            const int col = n0 + wc + ni * 16 + cc;
#pragma unroll
            for (int r = 0; r < 4; r++) {
                const int row = m0 + wr + mi * 16 + cr + r;
                P[(long long)row * N + col] = acc[mi][ni][r];
            }
        }
    }
}

// ---------------------------------------------------------------------------
// AV reduce: bf16 out = p0 + p1 (fp32 partials), vectorized
// ---------------------------------------------------------------------------
__global__ __launch_bounds__(256) void avred_kernel(
    const float4* __restrict__ p0, const float4* __restrict__ p1,
    ushort4* __restrict__ dst, int n4)
{
    int i = blockIdx.x * 256 + threadIdx.x;
    if (i < n4) {
        float4 a = p0[i], b = p1[i];
        ushort4 u;
        u.x = f2b(a.x + b.x); u.y = f2b(a.y + b.y);
        u.z = f2b(a.z + b.z); u.w = f2b(a.w + b.w);
        dst[i] = u;
    }
}

// ---------------------------------------------------------------------------
// Fused split-K reduce + bias + residual + LayerNorm.
// x = p0[row] + p1[row] + bias + resid[row]; out = LN(x)*g + b
// ---------------------------------------------------------------------------
template <int HAS_OUTB>
__global__ __launch_bounds__(256) void ln_red_kernel(
    const float* __restrict__ p0, const float* __restrict__ p1,
    const float* __restrict__ resid, const float* __restrict__ bias,
    const float* __restrict__ g, const float* __restrict__ b,
    float* __restrict__ out_f, unsigned short* __restrict__ out_b)
{
    __shared__ float red[8];
    const long long row = blockIdx.x;
    const int tid = threadIdx.x;
    const float4 a0 = ((const float4*)(p0 + row * D_))[tid];
    const float4 a1 = ((const float4*)(p1 + row * D_))[tid];
    const float4 rv = ((const float4*)(resid + row * D_))[tid];
    const float4 bi = ((const float4*)bias)[tid];
    float v0 = a0.x + a1.x + bi.x + rv.x;
    float v1 = a0.y + a1.y + bi.y + rv.y;
    float v2 = a0.z + a1.z + bi.z + rv.z;
    float v3 = a0.w + a1.w + bi.w + rv.w;

    float s = v0 + v1 + v2 + v3;
#pragma unroll
    for (int o = 32; o > 0; o >>= 1) s += __shfl_xor(s, o);
    if ((tid & 63) == 0) red[tid >> 6] = s;
    __syncthreads();
    const float mean = (red[0] + red[1] + red[2] + red[3]) * (1.0f / D_);

    const float d0 = v0 - mean, d1 = v1 - mean, d2 = v2 - mean, d3 = v3 - mean;
    float q = d0 * d0 + d1 * d1 + d2 * d2 + d3 * d3;
#pragma unroll
    for (int o = 32; o > 0; o >>= 1) q += __shfl_xor(q, o);
    if ((tid & 63) == 0) red[4 + (tid >> 6)] = q;
    __syncthreads();
    const float var = (red[4] + red[5] + red[6] + red[7]) * (1.0f / D_);
    const float inv = rsqrtf(var + 1e-6f);

    const float4 gv = ((const float4*)g)[tid];
    const float4 bv = ((const float4*)b)[tid];
    const float o0 = d0 * inv * gv.x + bv.x;
    const float o1 = d1 * inv * gv.y + bv.y;
    const float o2 = d2 * inv * gv.z + bv.z;
    const float o3 = d3 * inv * gv.w + bv.w;

    ((float4*)(out_f + row * D_))[tid] = float4{o0, o1, o2, o3};
    if (HAS_OUTB) {
        ushort4 u; u.x = f2b(o0); u.y = f2b(o1); u.z = f2b(o2); u.w = f2b(o3);
        ((ushort4*)(out_b + row * D_))[tid] = u;
    }
}

// ---------------------------------------------------------------------------
// softmax over rows of scores [B*S, S] + intensity, write bf16 attn
// ---------------------------------------------------------------------------
__global__ __launch_bounds__(256) void softmax_bias_kernel(
    const float* __restrict__ scores, const float* __restrict__ intensity,
    unsigned short* __restrict__ attn)
{
    __shared__ float red[8];
    const long long row = blockIdx.x;
    const int tid = threadIdx.x;
    const float4* s4 = (const float4*)(scores + row * S_);
    const float4* i4 = (const float4*)(intensity + row * S_);
    ushort4* dst = (ushort4*)(attn + row * S_);

    float vv[8];
    {
        float4 a = s4[tid], b = s4[tid + 256];
        vv[0] = a.x; vv[1] = a.y; vv[2] = a.z; vv[3] = a.w;
        vv[4] = b.x; vv[5] = b.y; vv[6] = b.z; vv[7] = b.w;
    }

    float mx = vv[0];
#pragma unroll
    for (int i = 1; i < 8; i++) mx = fmaxf(mx, vv[i]);
#pragma unroll
    for (int o = 32; o > 0; o >>= 1) mx = fmaxf(mx, __shfl_xor(mx, o));
    if ((tid & 63) == 0) red[tid >> 6] = mx;
    __syncthreads();
    mx = fmaxf(fmaxf(red[0], red[1]), fmaxf(red[2], red[3]));

    float e[8];
    float sum = 0.f;
#pragma unroll
    for (int i = 0; i < 8; i++) { e[i] = __expf(vv[i] - mx); sum += e[i]; }
#pragma unroll
    for (int o = 32; o > 0; o >>= 1) sum += __shfl_xor(sum, o);
    if ((tid & 63) == 0) red[4 + (tid >> 6)] = sum;
    __syncthreads();
    sum = red[4] + red[5] + red[6] + red[7];
    const float rs = 1.0f / sum;

#pragma unroll
    for (int i = 0; i < 2; i++) {
        float4 iv = i4[tid + 256 * i];
        ushort4 o;
        o.x = f2b(e[4 * i + 0] * rs + iv.x);
        o.y = f2b(e[4 * i + 1] * rs + iv.y);
        o.z = f2b(e[4 * i + 2] * rs + iv.z);
        o.w = f2b(e[4 * i + 3] * rs + iv.w);
        dst[tid + 256 * i] = o;
    }
}

// ---------------------------------------------------------------------------
// Fused QKV GEMM: A[8192,1024] @ Wqkvt[3072,1024]^T.
// seg 0 -> Qb bf16, seg 1 -> Kb bf16, seg 2 -> Vt[b][c][s] bf16
// ---------------------------------------------------------------------------
__global__ __launch_bounds__(256) void gemm_qkv(
    const unsigned short* __restrict__ A,
    const unsigned short* __restrict__ Bt,
    unsigned short* __restrict__ Qb,
    unsigned short* __restrict__ Kb,
    unsigned short* __restrict__ Vt,
    const float* __restrict__ bq,
    const float* __restrict__ bk,
    const float* __restrict__ bv)
{
    const int K = D_;
    __shared__ unsigned short As[128 * 32];
    __shared__ unsigned short Bs[128 * 32];

    const int tid  = threadIdx.x;
    const int lane = tid & 63;
    const int wave = tid >> 6;

    int bx = blockIdx.x, by = blockIdx.y;
    swizzle_xy(gridDim.x, gridDim.y, bx, by);
    const int m0 = by * 128;
    const int n0 = bx * 128;

    const int ra = tid >> 2;
    const int ca = (tid & 3) * 8;
    const unsigned short* gA = A  + (long long)(m0 + ra) * K + ca;
    const unsigned short* gB = Bt + (long long)(n0 + ra) * K + ca;
    const long long pass2 = 64LL * K;

    unsigned short* lA = &As[wave * 512];
    unsigned short* lB = &Bs[wave * 512];

    floatx4 acc[4][4];
#pragma unroll
    for (int i = 0; i < 4; i++)
#pragma unroll
        for (int j = 0; j < 4; j++) acc[i][j] = floatx4{0.f, 0.f, 0.f, 0.f};

    const int wr = (wave >> 1) * 64;
    const int wc = (wave & 1) * 64;
    const int fr = lane & 15;
    const int fk = (lane >> 4) * 8;

    for (int k0 = 0; k0 < K; k0 += 32) {
        __syncthreads();
        __builtin_amdgcn_global_load_lds(
            (const __attribute__((address_space(1))) void*)(gA + k0),
            (__attribute__((address_space(3))) void*)lA, 16, 0, 0);
        __builtin_amdgcn_global_load_lds(
            (const __attribute__((address_space(1))) void*)(gA + k0 + pass2),
            (__attribute__((address_space(3))) void*)(lA + 2048), 16, 0, 0);
        __builtin_amdgcn_global_load_lds(
            (const __attribute__((address_space(1))) void*)(gB + k0),
            (__attribute__((address_space(3))) void*)lB, 16, 0, 0);
        __builtin_amdgcn_global_load_lds(
            (const __attribute__((address_space(1))) void*)(gB + k0 + pass2),
            (__attribute__((address_space(3))) void*)(lB + 2048), 16, 0, 0);
        __syncthreads();

        short8 af[4], bfr[4];
#pragma unroll
        for (int mi = 0; mi < 4; mi++)
            af[mi] = *(const short8*)&As[(wr + mi * 16 + fr) * 32 + fk];
#pragma unroll
        for (int ni = 0; ni < 4; ni++)
            bfr[ni] = *(const short8*)&Bs[(wc + ni * 16 + fr) * 32 + fk];

#pragma unroll
        for (int mi = 0; mi < 4; mi++)
#pragma unroll
            for (int ni = 0; ni < 4; ni++)
                acc[mi][ni] = __builtin_amdgcn_mfma_f32_16x16x32_bf16(
                    af[mi], bfr[ni], acc[mi][ni], 0, 0, 0);
    }

    const int cr = (lane >> 4) * 4;
    const int cc = lane & 15;

#pragma unroll
    for (int mi = 0; mi < 4; mi++) {
#pragma unroll
        for (int ni = 0; ni < 4; ni++) {
            const int col = n0 + wc + ni * 16 + cc;
            const int seg = col >> 10;
            const int c = col & 1023;
            const float* bp = (seg == 0) ? bq : ((seg == 1) ? bk : bv);
            const float bval = bp[c];
#pragma unroll
            for (int r = 0; r < 4; r++) {
                const int row = m0 + wr + mi * 16 + cr + r;
                const unsigned short o = f2b(acc[mi][ni][r] + bval);
                if (seg == 0) {
                    Qb[(long long)row * D_ + c] = o;
                } else if (seg == 1) {
                    Kb[(long long)row * D_ + c] = o;
                } else {
                    const int b = row >> 11;
                    const int s = row & (S_ - 1);
                    Vt[((long long)b * D_ + c) * S_ + s] = o;
                }
            }
        }
    }
}

// ---------------------------------------------------------------------------
extern "C" void kernel_launch(void* const* d_in, const int* in_sizes, int n_in,
                              void* d_out, int out_size, void* d_ws, size_t ws_size,
                              hipStream_t stream)
{
    const float* X   = (const float*)d_in[0];
    const float* inten = (const float*)d_in[1];
    const float* Wq  = (const float*)d_in[2];
    const float* bq  = (const float*)d_in[3];
    const float* Wk  = (const float*)d_in[4];
    const float* bk  = (const float*)d_in[5];
    const float* Wv  = (const float*)d_in[6];
    const float* bv  = (const float*)d_in[7];
    const float* Wo  = (const float*)d_in[8];
    const float* bo  = (const float*)d_in[9];
    const float* W1  = (const float*)d_in[10];
    const float* b1  = (const float*)d_in[11];
    const float* W2  = (const float*)d_in[12];
    const float* b2  = (const float*)d_in[13];
    const float* g1  = (const float*)d_in[14];
    const float* be1 = (const float*)d_in[15];
    const float* g2  = (const float*)d_in[16];
    const float* be2 = (const float*)d_in[17];
    float* out = (float*)d_out;

    char* ws = (char*)d_ws;
    const size_t MB = 1ull << 20;
    // timeline-aliased layout, peak 216 MB:
    unsigned short* Xb   = (unsigned short*)(ws + 0);        // 16MB; dead after QKV
    unsigned short* Wqkv = (unsigned short*)(ws + 16 * MB);  // 6MB
    unsigned short* Wot  = (unsigned short*)(ws + 22 * MB);  // 2MB
    unsigned short* W1t  = (unsigned short*)(ws + 24 * MB);  // 8MB
    unsigned short* W2t  = (unsigned short*)(ws + 32 * MB);  // 8MB
    unsigned short* Qb   = (unsigned short*)(ws + 40 * MB);  // 16MB; dead after scores
    unsigned short* Kb   = (unsigned short*)(ws + 56 * MB);  // 16MB; dead after scores
    unsigned short* Vt   = (unsigned short*)(ws + 72 * MB);  // 16MB; dead after attnV
    float*          Sc   = (float*)(ws + 88 * MB);           // 64MB; dead after softmax
    unsigned short* At   = (unsigned short*)(ws + 152 * MB); // 32MB; dead after attnV
    float*          AVp  = (float*)(ws + 88 * MB);           // 64MB (2 parts; reuse Sc)
    unsigned short* AVb  = (unsigned short*)(ws + 0);        // 16MB (reuse Xb)
    float*          Op   = (float*)(ws + 152 * MB);          // 64MB (2 parts; reuse At)
    float*          Hf   = (float*)(ws + 40 * MB);           // 32MB (reuse Qb+Kb)
    unsigned short* Hb   = (unsigned short*)(ws + 72 * MB);  // 16MB (reuse Vt)
    unsigned short* F1   = (unsigned short*)(ws + 88 * MB);  // 64MB (reuse AVp)
    float*          Fp   = (float*)(ws + 152 * MB);          // 64MB (2 parts; reuse Op)

    const dim3 blk(256);
    const dim3 tblk(32, 8);
    const long long MN_av = (long long)B_ * S_ * D_;   // 8M elements per partial
    const long long MN_d  = (long long)B_ * S_ * D_;   // 8192x1024

    // casts / weight transposes
    cast_bf16_kernel<<<dim3(8192), blk, 0, stream>>>(
        (const float4*)X, (ushort4*)Xb, B_ * S_ * D_ / 4);
    transpose_cast_kernel<<<dim3(D_ / 32, D_ / 32), tblk, 0, stream>>>(
        Wq, Wqkv, D_, D_);
    transpose_cast_kernel<<<dim3(D_ / 32, D_ / 32), tblk, 0, stream>>>(
        Wk, Wqkv + 1024 * 1024, D_, D_);
    transpose_cast_kernel<<<dim3(D_ / 32, D_ / 32), tblk, 0, stream>>>(
        Wv, Wqkv + 2048 * 1024, D_, D_);
    transpose_cast_kernel<<<dim3(D_ / 32, D_ / 32), tblk, 0, stream>>>(Wo, Wot, D_, D_);
    transpose_cast_kernel<<<dim3(DFF_ / 32, D_ / 32), tblk, 0, stream>>>(W1, W1t, D_, DFF_);
    transpose_cast_kernel<<<dim3(D_ / 32, DFF_ / 32), tblk, 0, stream>>>(W2, W2t, DFF_, D_);

    // fused QKV: 1536 blocks (6/CU, 24 waves/CU)
    gemm_qkv<<<dim3(24, 64), blk, 0, stream>>>(Xb, Wqkv, Qb, Kb, Vt, bq, bk, bv);

    // scores = Q @ K^T / 32  (fp32, batched), 1024 blocks (16 waves/CU)
    gemm_bt<0, 0, 0><<<dim3(16, 16, 4), blk, 0, stream>>>(
        Qb, Kb, Sc, nullptr, S_, S_, D_, 0.03125f,
        (long long)S_ * D_, (long long)S_ * D_, (long long)S_ * S_);

    // attn = softmax(scores) + intensity  (bf16)
    softmax_bias_kernel<<<dim3(B_ * S_), blk, 0, stream>>>(Sc, inten, At);

    // AV split-K=2: z = b*2+ks, 1024 blocks (16 waves/CU), fp32 partials
    gemm_bt_sk<2><<<dim3(8, 16, 8), blk, 0, stream>>>(
        At, Vt, AVp, S_, D_, S_ / 2, S_, S_,
        (long long)S_ * S_, (long long)D_ * S_);
    // reduce partials -> bf16 AV
    avred_kernel<<<dim3(8192), blk, 0, stream>>>(
        (const float4*)AVp, (const float4*)(AVp + MN_av), (ushort4*)AVb,
        (int)(MN_av / 4));

    // O-proj split-K=2: 1024 blocks, fp32 partials
    gemm_bt_sk<2><<<dim3(8, 64, 2), blk, 0, stream>>>(
        AVb, Wot, Op, B_ * S_, D_, D_ / 2, D_, D_, 0, 0);

    // h = LN(Op0 + Op1 + bo + X)  -> Hf fp32 + Hb bf16
    ln_red_kernel<1><<<dim3(B_ * S_), blk, 0, stream>>>(
        Op, Op + MN_d, X, bo, g1, be1, Hf, Hb);

    // F1 = leaky_relu(h @ W1 + b1)  (bf16), 2048 blocks
    gemm_bt<1, 1, 1><<<dim3(32, 64), blk, 0, stream>>>(
        Hb, W1t, F1, b1, B_ * S_, DFF_, D_, 1.0f, 0, 0, 0);

    // ffn2 split-K=2: K=4096 -> 2x2048, 1024 blocks, fp32 partials
    gemm_bt_sk<2><<<dim3(8, 64, 2), blk, 0, stream>>>(
        F1, W2t, Fp, B_ * S_, D_, DFF_ / 2, DFF_, DFF_, 0, 0);

    // out = LN(Fp0 + Fp1 + b2 + h)
    ln_red_kernel<0><<<dim3(B_ * S_), blk, 0, stream>>>(
        Fp, Fp + MN_d, Hf, b2, g2, be2, out, nullptr);
}